// Round 11
// baseline (746.269 us; speedup 1.0000x reference)
//
#include <hip/hip_runtime.h>
#include <hip/hip_cooperative_groups.h>

namespace cg = cooperative_groups;

constexpr int C = 128;
#define SCAN_CHUNK 1024   // 256 threads x 4 items per scan block

typedef __attribute__((ext_vector_type(8))) short short8;   // 8 bf16 = 4 VGPR
typedef __attribute__((ext_vector_type(4))) float f32x4;
typedef __attribute__((ext_vector_type(2))) unsigned int u32x2;

__device__ __forceinline__ unsigned short f2bf(float f) {   // RNE f32->bf16
  unsigned int u = __float_as_uint(f);
  unsigned int r = (u + 0x7fffu + ((u >> 16) & 1u)) >> 16;
  return (unsigned short)r;
}
__device__ __forceinline__ float bfl(unsigned int p) { return __uint_as_float(p << 16); }
__device__ __forceinline__ float bfh(unsigned int p) { return __uint_as_float(p & 0xffff0000u); }

// ============ cooperative mega-kernel: prep + edges + scan + scatter + gather ====
__global__ __launch_bounds__(256, 8) void k_mega(
    const float* __restrict__ W, unsigned short* __restrict__ Wb,
    const float* __restrict__ h, unsigned short* __restrict__ hb, int total4,
    const int* __restrict__ dst, const float* __restrict__ ew,
    unsigned long long* __restrict__ packed, int* __restrict__ slot,
    const int* __restrict__ src, float* __restrict__ d, int* __restrict__ excl,
    int* __restrict__ sums, int2* __restrict__ meta,
    unsigned short* __restrict__ aggb, int n, int e, int nb, int edgeBlocks) {
  cg::grid_group grid = cg::this_grid();
  const int tid = threadIdx.x;
  const int gid = blockIdx.x * 256 + tid;
  const int T = gridDim.x * 256;
  __shared__ int l[256];
  __shared__ int preL[256];   // persists across phases (block stays resident)

  // ---- phase 0: zero packed; W -> bf16 ----
  for (int i = gid; i < n; i += T) packed[i] = 0ull;
  for (int i = gid; i < C * C / 4; i += T) {
    float4 w = ((const float4*)W)[i];
    uint2 pk;
    pk.x = f2bf(w.x) | ((unsigned int)f2bf(w.y) << 16);
    pk.y = f2bf(w.z) | ((unsigned int)f2bf(w.w) << 16);
    ((uint2*)Wb)[i] = pk;
  }
  grid.sync();

  // ---- phase 1 (block-range split): edge atomics  ||  h -> bf16 stream ----
  if (blockIdx.x < edgeBlocks) {
    const int Te = edgeBlocks * 256;
    for (int i = blockIdx.x * 256 + tid; i < e; i += Te) {
      unsigned long long enc =
          (1ull << 40) | (unsigned long long)(ew[i] * 4294967296.0f);
      unsigned long long old = atomicAdd(&packed[dst[i]], enc);
      slot[i] = (int)(old >> 40);
    }
  } else {
    const int Tc = (gridDim.x - edgeBlocks) * 256;
    for (int i = (blockIdx.x - edgeBlocks) * 256 + tid; i < total4; i += Tc) {
      f32x4 w = __builtin_nontemporal_load(&((const f32x4*)h)[i]);
      u32x2 pk;
      pk.x = f2bf(w.x) | ((unsigned int)f2bf(w.y) << 16);
      pk.y = f2bf(w.z) | ((unsigned int)f2bf(w.w) << 16);
      ((u32x2*)hb)[i] = pk;
    }
  }
  grid.sync();

  // ---- phase 2: per-chunk exclusive scan of counts + d = min(deg^-1/2,1e4) ----
  if (blockIdx.x < nb) {
    const int base = blockIdx.x * SCAN_CHUNK + tid * 4;
    int v0 = 0, v1 = 0, v2 = 0, v3 = 0;
    const float fs = 1.0f / 4294967296.0f;
    const unsigned long long M = (1ull << 40) - 1ull;
    if (base + 0 < n) { unsigned long long p = packed[base + 0]; v0 = (int)(p >> 40);
      d[base + 0] = fminf(1.0f / sqrtf(1.0f + (float)(p & M) * fs), 10000.0f); }
    if (base + 1 < n) { unsigned long long p = packed[base + 1]; v1 = (int)(p >> 40);
      d[base + 1] = fminf(1.0f / sqrtf(1.0f + (float)(p & M) * fs), 10000.0f); }
    if (base + 2 < n) { unsigned long long p = packed[base + 2]; v2 = (int)(p >> 40);
      d[base + 2] = fminf(1.0f / sqrtf(1.0f + (float)(p & M) * fs), 10000.0f); }
    if (base + 3 < n) { unsigned long long p = packed[base + 3]; v3 = (int)(p >> 40);
      d[base + 3] = fminf(1.0f / sqrtf(1.0f + (float)(p & M) * fs), 10000.0f); }
    const int s = v0 + v1 + v2 + v3;
    l[tid] = s; __syncthreads();
    for (int off = 1; off < 256; off <<= 1) {
      int x = 0;
      if (tid >= off) x = l[tid - off];
      __syncthreads();
      l[tid] += x;
      __syncthreads();
    }
    int ex = l[tid] - s;
    if (tid == 255) sums[blockIdx.x] = l[255];
    if (base + 0 < n) excl[base + 0] = ex;  ex += v0;
    if (base + 1 < n) excl[base + 1] = ex;  ex += v1;
    if (base + 2 < n) excl[base + 2] = ex;  ex += v2;
    if (base + 3 < n) excl[base + 3] = ex;
  }
  grid.sync();

  // ---- phase 3: every block builds preL (scan of <=256 block sums), then scatter ----
  {
    const int sv = (tid < nb) ? sums[tid] : 0;
    l[tid] = sv; __syncthreads();
    for (int off = 1; off < 256; off <<= 1) {
      int x = 0;
      if (tid >= off) x = l[tid - off];
      __syncthreads();
      l[tid] += x;
      __syncthreads();
    }
    preL[tid] = l[tid] - sv;
    __syncthreads();
    for (int i = gid; i < e; i += T) {
      int t = dst[i], s = src[i];
      float nm = d[s] * ew[i] * d[t];
      int p = excl[t] + preL[t >> 10] + slot[i];
      meta[p] = make_int2(s, __float_as_int(nm));
    }
  }
  grid.sync();

  // ---- phase 4: gather-aggregate (32 lanes per dst node, unroll-4, bf16 in/out) ----
  {
    const int items = n * 32;
    const u32x2* mp = (const u32x2*)meta;
    for (int it = gid; it < items; it += T) {
      const int v = it >> 5, lane = it & 31;
      const int cb = lane * 4;
      const float dv = d[v];
      const float dd = dv * dv;
      uint2 hv = *(const uint2*)(hb + (size_t)v * C + cb);
      float4 acc = make_float4(bfl(hv.x) * dd, bfh(hv.x) * dd,
                               bfl(hv.y) * dd, bfh(hv.y) * dd);
      int p = excl[v] + preL[v >> 10];
      const int end = (v + 1 < n) ? (excl[v + 1] + preL[(v + 1) >> 10]) : e;
      for (; p + 4 <= end; p += 4) {
        u32x2 m0 = __builtin_nontemporal_load(mp + p);
        u32x2 m1 = __builtin_nontemporal_load(mp + p + 1);
        u32x2 m2 = __builtin_nontemporal_load(mp + p + 2);
        u32x2 m3 = __builtin_nontemporal_load(mp + p + 3);
        float n0 = __uint_as_float(m0.y), n1 = __uint_as_float(m1.y);
        float n2 = __uint_as_float(m2.y), n3 = __uint_as_float(m3.y);
        uint2 x0 = *(const uint2*)(hb + (size_t)m0.x * C + cb);
        uint2 x1 = *(const uint2*)(hb + (size_t)m1.x * C + cb);
        uint2 x2 = *(const uint2*)(hb + (size_t)m2.x * C + cb);
        uint2 x3 = *(const uint2*)(hb + (size_t)m3.x * C + cb);
        acc.x += bfl(x0.x) * n0 + bfl(x1.x) * n1 + bfl(x2.x) * n2 + bfl(x3.x) * n3;
        acc.y += bfh(x0.x) * n0 + bfh(x1.x) * n1 + bfh(x2.x) * n2 + bfh(x3.x) * n3;
        acc.z += bfl(x0.y) * n0 + bfl(x1.y) * n1 + bfl(x2.y) * n2 + bfl(x3.y) * n3;
        acc.w += bfh(x0.y) * n0 + bfh(x1.y) * n1 + bfh(x2.y) * n2 + bfh(x3.y) * n3;
      }
      for (; p < end; ++p) {
        u32x2 m0 = __builtin_nontemporal_load(mp + p);
        float n0 = __uint_as_float(m0.y);
        uint2 x0 = *(const uint2*)(hb + (size_t)m0.x * C + cb);
        acc.x += bfl(x0.x) * n0; acc.y += bfh(x0.x) * n0;
        acc.z += bfl(x0.y) * n0; acc.w += bfh(x0.y) * n0;
      }
      u32x2 pk;
      pk.x = f2bf(acc.x) | ((unsigned int)f2bf(acc.y) << 16);
      pk.y = f2bf(acc.z) | ((unsigned int)f2bf(acc.w) << 16);
      __builtin_nontemporal_store(pk, (u32x2*)(aggb + (size_t)v * C + cb));
    }
  }
}

// ============ fallback path kernels (R10 structure) ==============================
template <int DO_HB>
__global__ void k_prep_all(const float* __restrict__ W, unsigned short* __restrict__ Wb,
                           const float* __restrict__ h, unsigned short* __restrict__ hb,
                           int total4, unsigned long long* __restrict__ packed, int n) {
  const int stride = gridDim.x * blockDim.x;
  const int gid = blockIdx.x * blockDim.x + threadIdx.x;
  for (int i = gid; i < C * C / 4; i += stride) {
    float4 w = ((const float4*)W)[i];
    uint2 pk;
    pk.x = f2bf(w.x) | ((unsigned int)f2bf(w.y) << 16);
    pk.y = f2bf(w.z) | ((unsigned int)f2bf(w.w) << 16);
    ((uint2*)Wb)[i] = pk;
  }
  if (DO_HB) {
    for (int i = gid; i < total4; i += stride) {
      f32x4 w = __builtin_nontemporal_load(&((const f32x4*)h)[i]);
      u32x2 pk;
      pk.x = f2bf(w.x) | ((unsigned int)f2bf(w.y) << 16);
      pk.y = f2bf(w.z) | ((unsigned int)f2bf(w.w) << 16);
      ((u32x2*)hb)[i] = pk;
    }
  }
  for (int i = gid; i < n; i += stride) packed[i] = 0ull;
}

__global__ void k_edge_deg(const int* __restrict__ dst, const float* __restrict__ ew,
                           unsigned long long* __restrict__ packed,
                           int* __restrict__ slot, int e) {
  int i = blockIdx.x * blockDim.x + threadIdx.x;
  if (i < e) {
    unsigned long long enc =
        (1ull << 40) | (unsigned long long)(ew[i] * 4294967296.0f);
    unsigned long long old = atomicAdd(&packed[dst[i]], enc);
    slot[i] = (int)(old >> 40);
  }
}

__global__ void k_scan1(const unsigned long long* __restrict__ packed,
                        float* __restrict__ d, int* __restrict__ excl,
                        int* __restrict__ sums, int n) {
  __shared__ int l[256];
  const int t = threadIdx.x;
  const int base = blockIdx.x * SCAN_CHUNK + t * 4;
  int v0 = 0, v1 = 0, v2 = 0, v3 = 0;
  const float fs = 1.0f / 4294967296.0f;
  const unsigned long long M = (1ull << 40) - 1ull;
  if (base + 0 < n) { unsigned long long p = packed[base + 0]; v0 = (int)(p >> 40);
    d[base + 0] = fminf(1.0f / sqrtf(1.0f + (float)(p & M) * fs), 10000.0f); }
  if (base + 1 < n) { unsigned long long p = packed[base + 1]; v1 = (int)(p >> 40);
    d[base + 1] = fminf(1.0f / sqrtf(1.0f + (float)(p & M) * fs), 10000.0f); }
  if (base + 2 < n) { unsigned long long p = packed[base + 2]; v2 = (int)(p >> 40);
    d[base + 2] = fminf(1.0f / sqrtf(1.0f + (float)(p & M) * fs), 10000.0f); }
  if (base + 3 < n) { unsigned long long p = packed[base + 3]; v3 = (int)(p >> 40);
    d[base + 3] = fminf(1.0f / sqrtf(1.0f + (float)(p & M) * fs), 10000.0f); }
  const int s = v0 + v1 + v2 + v3;
  l[t] = s; __syncthreads();
  for (int off = 1; off < 256; off <<= 1) {
    int x = 0;
    if (t >= off) x = l[t - off];
    __syncthreads();
    l[t] += x;
    __syncthreads();
  }
  int ex = l[t] - s;
  if (t == 255) sums[blockIdx.x] = l[t];
  if (base + 0 < n) excl[base + 0] = ex;  ex += v0;
  if (base + 1 < n) excl[base + 1] = ex;  ex += v1;
  if (base + 2 < n) excl[base + 2] = ex;  ex += v2;
  if (base + 3 < n) excl[base + 3] = ex;
}

__global__ void k_scan23(int* __restrict__ rowptr, const int* __restrict__ sums,
                         int nb, int n, int e) {
  __shared__ int l[256];
  __shared__ int pre[256];
  const int t = threadIdx.x;
  const int s = (t < nb) ? sums[t] : 0;
  l[t] = s; __syncthreads();
  for (int off = 1; off < 256; off <<= 1) {
    int x = 0;
    if (t >= off) x = l[t - off];
    __syncthreads();
    l[t] += x;
    __syncthreads();
  }
  pre[t] = l[t] - s;
  __syncthreads();
  const int i = blockIdx.x * 256 + t;
  if (i < n) rowptr[i] += pre[i >> 10];
  else if (i == n) rowptr[n] = e;
}

__global__ void k_scatter(const int* __restrict__ src, const int* __restrict__ dst,
                          const float* __restrict__ ew, const float* __restrict__ d,
                          const int* __restrict__ rowptr, const int* __restrict__ slot,
                          int2* __restrict__ meta, int e) {
  int i = blockIdx.x * blockDim.x + threadIdx.x;
  if (i < e) {
    int t = dst[i], s = src[i];
    float nm = d[s] * ew[i] * d[t];
    int p = rowptr[t] + slot[i];
    meta[p] = make_int2(s, __float_as_int(nm));
  }
}

template <int USE_HB, int OUT_BF>
__global__ void k_gather(const int* __restrict__ rowptr, const int2* __restrict__ meta,
                         const float* __restrict__ d, const float* __restrict__ h,
                         const unsigned short* __restrict__ hb,
                         float* __restrict__ aggf, unsigned short* __restrict__ aggb,
                         int n) {
  int g = blockIdx.x * blockDim.x + threadIdx.x;
  int v = g >> 5, lane = g & 31;
  if (v >= n) return;
  const int cb = lane * 4;
  const float dv = d[v];
  const float dd = dv * dv;
  const u32x2* mp = (const u32x2*)meta;
  float4 acc;
  if (USE_HB) {
    uint2 hv = *(const uint2*)(hb + (size_t)v * C + cb);
    acc = make_float4(bfl(hv.x) * dd, bfh(hv.x) * dd, bfl(hv.y) * dd, bfh(hv.y) * dd);
  } else {
    float4 hv = *(const float4*)(h + (size_t)v * C + cb);
    acc = make_float4(hv.x * dd, hv.y * dd, hv.z * dd, hv.w * dd);
  }
  int p = rowptr[v];
  const int end = rowptr[v + 1];
  if (USE_HB) {
    for (; p + 4 <= end; p += 4) {
      u32x2 m0 = __builtin_nontemporal_load(mp + p);
      u32x2 m1 = __builtin_nontemporal_load(mp + p + 1);
      u32x2 m2 = __builtin_nontemporal_load(mp + p + 2);
      u32x2 m3 = __builtin_nontemporal_load(mp + p + 3);
      float n0 = __uint_as_float(m0.y), n1 = __uint_as_float(m1.y);
      float n2 = __uint_as_float(m2.y), n3 = __uint_as_float(m3.y);
      uint2 x0 = *(const uint2*)(hb + (size_t)m0.x * C + cb);
      uint2 x1 = *(const uint2*)(hb + (size_t)m1.x * C + cb);
      uint2 x2 = *(const uint2*)(hb + (size_t)m2.x * C + cb);
      uint2 x3 = *(const uint2*)(hb + (size_t)m3.x * C + cb);
      acc.x += bfl(x0.x) * n0 + bfl(x1.x) * n1 + bfl(x2.x) * n2 + bfl(x3.x) * n3;
      acc.y += bfh(x0.x) * n0 + bfh(x1.x) * n1 + bfh(x2.x) * n2 + bfh(x3.x) * n3;
      acc.z += bfl(x0.y) * n0 + bfl(x1.y) * n1 + bfl(x2.y) * n2 + bfl(x3.y) * n3;
      acc.w += bfh(x0.y) * n0 + bfh(x1.y) * n1 + bfh(x2.y) * n2 + bfh(x3.y) * n3;
    }
    for (; p < end; ++p) {
      u32x2 m0 = __builtin_nontemporal_load(mp + p);
      float n0 = __uint_as_float(m0.y);
      uint2 x0 = *(const uint2*)(hb + (size_t)m0.x * C + cb);
      acc.x += bfl(x0.x) * n0; acc.y += bfh(x0.x) * n0;
      acc.z += bfl(x0.y) * n0; acc.w += bfh(x0.y) * n0;
    }
  } else {
    for (; p + 4 <= end; p += 4) {
      u32x2 m0 = __builtin_nontemporal_load(mp + p);
      u32x2 m1 = __builtin_nontemporal_load(mp + p + 1);
      u32x2 m2 = __builtin_nontemporal_load(mp + p + 2);
      u32x2 m3 = __builtin_nontemporal_load(mp + p + 3);
      float n0 = __uint_as_float(m0.y), n1 = __uint_as_float(m1.y);
      float n2 = __uint_as_float(m2.y), n3 = __uint_as_float(m3.y);
      float4 x0 = *(const float4*)(h + (size_t)m0.x * C + cb);
      float4 x1 = *(const float4*)(h + (size_t)m1.x * C + cb);
      float4 x2 = *(const float4*)(h + (size_t)m2.x * C + cb);
      float4 x3 = *(const float4*)(h + (size_t)m3.x * C + cb);
      acc.x += x0.x * n0 + x1.x * n1 + x2.x * n2 + x3.x * n3;
      acc.y += x0.y * n0 + x1.y * n1 + x2.y * n2 + x3.y * n3;
      acc.z += x0.z * n0 + x1.z * n1 + x2.z * n2 + x3.z * n3;
      acc.w += x0.w * n0 + x1.w * n1 + x2.w * n2 + x3.w * n3;
    }
    for (; p < end; ++p) {
      u32x2 m0 = __builtin_nontemporal_load(mp + p);
      float n0 = __uint_as_float(m0.y);
      float4 x0 = *(const float4*)(h + (size_t)m0.x * C + cb);
      acc.x += x0.x * n0; acc.y += x0.y * n0; acc.z += x0.z * n0; acc.w += x0.w * n0;
    }
  }
  if (OUT_BF) {
    u32x2 pk;
    pk.x = f2bf(acc.x) | ((unsigned int)f2bf(acc.y) << 16);
    pk.y = f2bf(acc.z) | ((unsigned int)f2bf(acc.w) << 16);
    __builtin_nontemporal_store(pk, (u32x2*)(aggb + (size_t)v * C + cb));
  } else {
    *(float4*)(aggf + (size_t)v * C + cb) = acc;
  }
}

// ---- x = agg @ W^T + b + h ; LN ; exact GELU  (bf16 MFMA, D = W·agg^T) ----
#define TM 64

template <int IN_BF, int RES_BF>
__launch_bounds__(256, 3)
__global__ void k_mfma_ln_gelu(const float* __restrict__ aggf,
                               const unsigned short* __restrict__ aggb,
                               const float* __restrict__ h,
                               const unsigned short* __restrict__ hb,
                               const unsigned short* __restrict__ Wb,
                               const float* __restrict__ b,
                               const float* __restrict__ gamma, const float* __restrict__ beta,
                               float* __restrict__ out, int n) {
  __shared__ char lds[48 * 1024];
  char* Wl = lds;              // 32 KB bf16 [128][128], swizzled
  char* Al = lds + 32768;      // 16 KB bf16 [64][128],  swizzled
  const int tid = threadIdx.x;
  const int row0 = blockIdx.x * TM;

  #pragma unroll
  for (int i = 0; i < 8; ++i) {
    int u = tid + i * 256;
    int j = u >> 4, un = u & 15;
    uint4 w = ((const uint4*)Wb)[u];
    *(uint4*)(Wl + j * 256 + ((un * 16) ^ ((j & 7) << 4))) = w;
  }
  #pragma unroll
  for (int i = 0; i < 8; ++i) {
    int u = tid + i * 256;
    int j = u >> 5;
    int rr = row0 + j; if (rr >= n) rr = n - 1;
    uint2 pk;
    if (IN_BF) {
      pk = ((const uint2*)(aggb + (size_t)rr * C))[u & 31];
    } else {
      float4 a = ((const float4*)(aggf + (size_t)rr * C))[u & 31];
      pk.x = f2bf(a.x) | ((unsigned int)f2bf(a.y) << 16);
      pk.y = f2bf(a.z) | ((unsigned int)f2bf(a.w) << 16);
    }
    *(uint2*)(Al + j * 256 + (((u & 31) * 8) ^ ((j & 7) << 4))) = pk;
  }
  __syncthreads();

  const int lane = tid & 63;
  const int wt   = tid >> 6;
  const int c16  = lane & 15;    // node index within wave tile
  const int quad = lane >> 4;    // col sub-block: j = jt*16 + quad*4 + i

  f32x4 acc[8];
  #pragma unroll
  for (int jt = 0; jt < 8; ++jt) acc[jt] = (f32x4){0.f, 0.f, 0.f, 0.f};

  const int abase = (wt * 16 + c16) * 256;
  const int swz   = (c16 & 7) << 4;
  #pragma unroll
  for (int ks = 0; ks < 4; ++ks) {
    const int koff = ks * 64 + quad * 16;
    short8 af_agg = *(const short8*)(Al + abase + (koff ^ swz));
    #pragma unroll
    for (int jt = 0; jt < 8; ++jt) {
      short8 af_w = *(const short8*)(Wl + (jt * 16 + c16) * 256 + (koff ^ swz));
      acc[jt] = __builtin_amdgcn_mfma_f32_16x16x32_bf16(af_w, af_agg, acc[jt], 0, 0, 0);
    }
  }

  const int node = row0 + wt * 16 + c16;
  const bool ok = node < n;
  const int jb = quad * 4;
  float s = 0.f, t2 = 0.f;
  #pragma unroll
  for (int jt = 0; jt < 8; ++jt) {
    const int j = jt * 16 + jb;
    float4 b4 = *(const float4*)(b + j);
    float r0 = 0.f, r1 = 0.f, r2 = 0.f, r3 = 0.f;
    if (ok) {
      if (RES_BF) {
        uint2 rh = *(const uint2*)(hb + (size_t)node * C + j);
        r0 = bfl(rh.x); r1 = bfh(rh.x); r2 = bfl(rh.y); r3 = bfh(rh.y);
      } else {
        float4 rh = *(const float4*)(h + (size_t)node * C + j);
        r0 = rh.x; r1 = rh.y; r2 = rh.z; r3 = rh.w;
      }
    }
    acc[jt][0] += b4.x + r0;
    acc[jt][1] += b4.y + r1;
    acc[jt][2] += b4.z + r2;
    acc[jt][3] += b4.w + r3;
    #pragma unroll
    for (int i = 0; i < 4; ++i) { float v = acc[jt][i]; s += v; t2 += v * v; }
  }
  s  += __shfl_xor(s, 16);  t2 += __shfl_xor(t2, 16);
  s  += __shfl_xor(s, 32);  t2 += __shfl_xor(t2, 32);
  const float inv = 1.0f / C;
  const float mean = s * inv;
  const float var  = t2 * inv - mean * mean;
  const float rstd = rsqrtf(var + 1e-5f);
  if (ok) {
    float* orow = out + (size_t)node * C;
    #pragma unroll
    for (int jt = 0; jt < 8; ++jt) {
      const int j = jt * 16 + jb;
      float4 g4  = *(const float4*)(gamma + j);
      float4 be4 = *(const float4*)(beta + j);
      float4 o;
      float y;
      y = g4.x * ((acc[jt][0] - mean) * rstd) + be4.x; o.x = 0.5f * y * (1.0f + erff(y * 0.70710678118f));
      y = g4.y * ((acc[jt][1] - mean) * rstd) + be4.y; o.y = 0.5f * y * (1.0f + erff(y * 0.70710678118f));
      y = g4.z * ((acc[jt][2] - mean) * rstd) + be4.z; o.z = 0.5f * y * (1.0f + erff(y * 0.70710678118f));
      y = g4.w * ((acc[jt][3] - mean) * rstd) + be4.w; o.w = 0.5f * y * (1.0f + erff(y * 0.70710678118f));
      *(float4*)(orow + j) = o;
    }
  }
}

extern "C" void kernel_launch(void* const* d_in, const int* in_sizes, int n_in,
                              void* d_out, int out_size, void* d_ws, size_t ws_size,
                              hipStream_t stream) {
  const float* h     = (const float*)d_in[0];
  const int*   ei    = (const int*)d_in[1];
  const float* ew    = (const float*)d_in[2];
  const float* W     = (const float*)d_in[3];
  const float* b     = (const float*)d_in[4];
  const float* gamma = (const float*)d_in[5];
  const float* beta  = (const float*)d_in[6];

  const int n = in_sizes[0] / C;
  const int e = in_sizes[2];
  const int* src = ei;
  const int* dst = ei + e;

  float* out = (float*)d_out;

  // workspace layout
  int2* meta    = (int2*)d_ws;                          // e
  unsigned long long* packed = (unsigned long long*)(meta + e);  // n (8B aligned)
  int* slot     = (int*)(packed + n);                   // e
  float* d      = (float*)(slot + e);                   // n
  int* rowptr   = (int*)(d + n);                        // n+1 (coop: unapplied excl)
  int* sums     = rowptr + (n + 1);                     // <=256
  unsigned short* Wb = (unsigned short*)(sums + 256);   // C*C
  unsigned short* hb = Wb + C * C;                      // n*C
  unsigned short* aggb = hb + (size_t)n * C;            // n*C

  const size_t need_mid  = (size_t)((char*)(hb + (size_t)n * C) - (char*)d_ws);
  const size_t need_full = (size_t)((char*)(aggb + (size_t)n * C) - (char*)d_ws);
  const int mode = (ws_size >= need_full) ? 2 : (ws_size >= need_mid) ? 1 : 0;

  const int nb = (n + SCAN_CHUNK - 1) / SCAN_CHUNK;
  const int total4 = n * C / 4;
  const int mgrid = (n + TM - 1) / TM;

  // ---- cooperative fast path (mode 2 only) ----
  bool done_front = false;
  if (mode == 2) {
    int dev = 0;
    hipGetDevice(&dev);
    int coop = 0;
    hipDeviceGetAttribute(&coop, hipDeviceAttributeCooperativeLaunch, dev);
    if (coop) {
      int maxB = 0;
      if (hipOccupancyMaxActiveBlocksPerMultiprocessor(&maxB, k_mega, 256, 0) == hipSuccess
          && maxB > 0) {
        int numCU = 0;
        hipDeviceGetAttribute(&numCU, hipDeviceAttributeMultiprocessorCount, dev);
        int grid = numCU * maxB;
        if (grid > 4096) grid = 4096;
        if (grid >= nb) {
          int edgeBlocks = grid / 4;
          const float* aW = W; unsigned short* aWb = Wb;
          const float* ah = h; unsigned short* ahb = hb; int atotal4 = total4;
          const int* adst = dst; const float* aew = ew;
          unsigned long long* apacked = packed; int* aslot = slot;
          const int* asrc = src; float* ad = d; int* aexcl = rowptr;
          int* asums = sums; int2* ameta = meta; unsigned short* aaggb = aggb;
          int an = n, ae = e, anb = nb, aeb = edgeBlocks;
          void* args[] = { &aW, &aWb, &ah, &ahb, &atotal4, &adst, &aew,
                           &apacked, &aslot, &asrc, &ad, &aexcl, &asums,
                           &ameta, &aaggb, &an, &ae, &anb, &aeb };
          if (hipLaunchCooperativeKernel((void*)k_mega, dim3(grid), dim3(256),
                                         args, 0, stream) == hipSuccess) {
            done_front = true;
          }
        }
      }
    }
  }

  if (done_front) {
    k_mfma_ln_gelu<1, 1><<<mgrid, 256, 0, stream>>>(out, aggb, h, hb, Wb, b, gamma, beta, out, n);
    return;
  }

  // ---- fallback: R10 multi-kernel path ----
  if (mode >= 1)
    k_prep_all<1><<<1024, 256, 0, stream>>>(W, Wb, h, hb, total4, packed, n);
  else
    k_prep_all<0><<<1024, 256, 0, stream>>>(W, Wb, h, hb, total4, packed, n);

  k_edge_deg<<<(e + 255) / 256, 256, 0, stream>>>(dst, ew, packed, slot, e);
  k_scan1   <<<nb, 256, 0, stream>>>(packed, d, rowptr, sums, n);
  k_scan23  <<<(n + 256) / 256, 256, 0, stream>>>(rowptr, sums, nb, n, e);
  k_scatter <<<(e + 255) / 256, 256, 0, stream>>>(src, dst, ew, d, rowptr, slot, meta, e);

  const long gthreads = (long)n * 32;
  const int ggrid = (int)((gthreads + 255) / 256);

  if (mode == 2) {
    k_gather<1, 1><<<ggrid, 256, 0, stream>>>(rowptr, meta, d, h, hb, out, aggb, n);
    k_mfma_ln_gelu<1, 1><<<mgrid, 256, 0, stream>>>(out, aggb, h, hb, Wb, b, gamma, beta, out, n);
  } else if (mode == 1) {
    k_gather<1, 0><<<ggrid, 256, 0, stream>>>(rowptr, meta, d, h, hb, out, aggb, n);
    k_mfma_ln_gelu<0, 1><<<mgrid, 256, 0, stream>>>(out, aggb, h, hb, Wb, b, gamma, beta, out, n);
  } else {
    k_gather<0, 0><<<ggrid, 256, 0, stream>>>(rowptr, meta, d, h, hb, out, aggb, n);
    k_mfma_ln_gelu<0, 0><<<mgrid, 256, 0, stream>>>(out, aggb, h, hb, Wb, b, gamma, beta, out, n);
  }
}

// Round 12
// 139.278 us; speedup vs baseline: 5.3581x; 5.3581x over previous
//
#include <hip/hip_runtime.h>

constexpr int C = 128;
#define SCAN_CHUNK 1024   // 256 threads x 4 items per scan block

typedef __attribute__((ext_vector_type(8))) short short8;   // 8 bf16 = 4 VGPR
typedef __attribute__((ext_vector_type(4))) float f32x4;

__device__ __forceinline__ unsigned short f2bf(float f) {   // RNE f32->bf16
  unsigned int u = __float_as_uint(f);
  unsigned int r = (u + 0x7fffu + ((u >> 16) & 1u)) >> 16;
  return (unsigned short)r;
}
__device__ __forceinline__ float bfl(unsigned int p) { return __uint_as_float(p << 16); }
__device__ __forceinline__ float bfh(unsigned int p) { return __uint_as_float(p & 0xffff0000u); }

// ---- kA: fused prep: W->bf16, (h->bf16), packed=0 ----
template <int DO_HB>
__global__ void k_prep_all(const float* __restrict__ W, unsigned short* __restrict__ Wb,
                           const float* __restrict__ h, unsigned short* __restrict__ hb,
                           int total4, unsigned long long* __restrict__ packed, int n) {
  const int stride = gridDim.x * blockDim.x;
  const int gid = blockIdx.x * blockDim.x + threadIdx.x;
  for (int i = gid; i < C * C / 4; i += stride) {
    float4 w = ((const float4*)W)[i];
    uint2 pk;
    pk.x = f2bf(w.x) | ((unsigned int)f2bf(w.y) << 16);
    pk.y = f2bf(w.z) | ((unsigned int)f2bf(w.w) << 16);
    ((uint2*)Wb)[i] = pk;
  }
  if (DO_HB) {
    for (int i = gid; i < total4; i += stride) {
      float4 w = ((const float4*)h)[i];
      uint2 pk;
      pk.x = f2bf(w.x) | ((unsigned int)f2bf(w.y) << 16);
      pk.y = f2bf(w.z) | ((unsigned int)f2bf(w.w) << 16);
      ((uint2*)hb)[i] = pk;
    }
  }
  for (int i = gid; i < n; i += stride) packed[i] = 0ull;
}

// ---- kB: one u64 atomic per edge: packed[t] += (1<<40) | fixed32(ew).
// Returned old value gives the CSR slot (old>>40) for free.
__global__ void k_edge_deg(const int* __restrict__ dst, const float* __restrict__ ew,
                           unsigned long long* __restrict__ packed,
                           int* __restrict__ slot, int e) {
  int i = blockIdx.x * blockDim.x + threadIdx.x;
  if (i < e) {
    unsigned long long enc =
        (1ull << 40) | (unsigned long long)(ew[i] * 4294967296.0f);
    unsigned long long old = atomicAdd(&packed[dst[i]], enc);
    slot[i] = (int)(old >> 40);
  }
}

// ---- kC: scan1 over counts (packed>>40) + compute d = min(deg^-1/2,1e4) ----
__global__ void k_scan1(const unsigned long long* __restrict__ packed,
                        float* __restrict__ d, int* __restrict__ excl,
                        int* __restrict__ sums, int n) {
  __shared__ int l[256];
  const int t = threadIdx.x;
  const int base = blockIdx.x * SCAN_CHUNK + t * 4;
  int v0 = 0, v1 = 0, v2 = 0, v3 = 0;
  const float fs = 1.0f / 4294967296.0f;
  const unsigned long long M = (1ull << 40) - 1ull;
  if (base + 0 < n) { unsigned long long p = packed[base + 0]; v0 = (int)(p >> 40);
    d[base + 0] = fminf(1.0f / sqrtf(1.0f + (float)(p & M) * fs), 10000.0f); }
  if (base + 1 < n) { unsigned long long p = packed[base + 1]; v1 = (int)(p >> 40);
    d[base + 1] = fminf(1.0f / sqrtf(1.0f + (float)(p & M) * fs), 10000.0f); }
  if (base + 2 < n) { unsigned long long p = packed[base + 2]; v2 = (int)(p >> 40);
    d[base + 2] = fminf(1.0f / sqrtf(1.0f + (float)(p & M) * fs), 10000.0f); }
  if (base + 3 < n) { unsigned long long p = packed[base + 3]; v3 = (int)(p >> 40);
    d[base + 3] = fminf(1.0f / sqrtf(1.0f + (float)(p & M) * fs), 10000.0f); }
  const int s = v0 + v1 + v2 + v3;
  l[t] = s; __syncthreads();
  for (int off = 1; off < 256; off <<= 1) {
    int x = 0;
    if (t >= off) x = l[t - off];
    __syncthreads();
    l[t] += x;
    __syncthreads();
  }
  int ex = l[t] - s;
  if (t == 255) sums[blockIdx.x] = l[t];
  if (base + 0 < n) excl[base + 0] = ex;  ex += v0;
  if (base + 1 < n) excl[base + 1] = ex;  ex += v1;
  if (base + 2 < n) excl[base + 2] = ex;  ex += v2;
  if (base + 3 < n) excl[base + 3] = ex;
}

__global__ void k_scan2(int* __restrict__ sums, int nb) {  // nb <= 256
  __shared__ int l[256];
  const int t = threadIdx.x;
  const int s = (t < nb) ? sums[t] : 0;
  l[t] = s; __syncthreads();
  for (int off = 1; off < 256; off <<= 1) {
    int x = 0;
    if (t >= off) x = l[t - off];
    __syncthreads();
    l[t] += x;
    __syncthreads();
  }
  if (t < nb) sums[t] = l[t] - s;
}

__global__ void k_scan3(int* __restrict__ rowptr, const int* __restrict__ sums,
                        int n, int e) {
  int i = blockIdx.x * blockDim.x + threadIdx.x;
  if (i < n) rowptr[i] += sums[i >> 10];
  if (i == 0) rowptr[n] = e;
}

// ---- kF: scatter (no atomics): p = rowptr[dst] + slot ----
__global__ void k_scatter(const int* __restrict__ src, const int* __restrict__ dst,
                          const float* __restrict__ ew, const float* __restrict__ d,
                          const int* __restrict__ rowptr, const int* __restrict__ slot,
                          int2* __restrict__ meta, int e) {
  int i = blockIdx.x * blockDim.x + threadIdx.x;
  if (i < e) {
    int t = dst[i], s = src[i];
    float nm = d[s] * ew[i] * d[t];
    int p = rowptr[t] + slot[i];
    meta[p] = make_int2(s, __float_as_int(nm));
  }
}

// ---- kG: gather-aggregate, 32 lanes per dst node, unroll-4 ----
template <int USE_HB, int OUT_BF>
__global__ void k_gather(const int* __restrict__ rowptr, const int2* __restrict__ meta,
                         const float* __restrict__ d, const float* __restrict__ h,
                         const unsigned short* __restrict__ hb,
                         float* __restrict__ aggf, unsigned short* __restrict__ aggb,
                         int n) {
  int g = blockIdx.x * blockDim.x + threadIdx.x;
  int v = g >> 5, lane = g & 31;
  if (v >= n) return;
  const int cb = lane * 4;
  const float dv = d[v];
  const float dd = dv * dv;
  float4 acc;
  if (USE_HB) {
    uint2 hv = *(const uint2*)(hb + (size_t)v * C + cb);
    acc = make_float4(bfl(hv.x) * dd, bfh(hv.x) * dd, bfl(hv.y) * dd, bfh(hv.y) * dd);
  } else {
    float4 hv = *(const float4*)(h + (size_t)v * C + cb);
    acc = make_float4(hv.x * dd, hv.y * dd, hv.z * dd, hv.w * dd);
  }
  int p = rowptr[v];
  const int end = rowptr[v + 1];
  if (USE_HB) {
    for (; p + 4 <= end; p += 4) {
      int2 m0 = meta[p], m1 = meta[p + 1], m2 = meta[p + 2], m3 = meta[p + 3];
      float n0 = __int_as_float(m0.y), n1 = __int_as_float(m1.y);
      float n2 = __int_as_float(m2.y), n3 = __int_as_float(m3.y);
      uint2 x0 = *(const uint2*)(hb + (size_t)m0.x * C + cb);
      uint2 x1 = *(const uint2*)(hb + (size_t)m1.x * C + cb);
      uint2 x2 = *(const uint2*)(hb + (size_t)m2.x * C + cb);
      uint2 x3 = *(const uint2*)(hb + (size_t)m3.x * C + cb);
      acc.x += bfl(x0.x) * n0 + bfl(x1.x) * n1 + bfl(x2.x) * n2 + bfl(x3.x) * n3;
      acc.y += bfh(x0.x) * n0 + bfh(x1.x) * n1 + bfh(x2.x) * n2 + bfh(x3.x) * n3;
      acc.z += bfl(x0.y) * n0 + bfl(x1.y) * n1 + bfl(x2.y) * n2 + bfl(x3.y) * n3;
      acc.w += bfh(x0.y) * n0 + bfh(x1.y) * n1 + bfh(x2.y) * n2 + bfh(x3.y) * n3;
    }
    for (; p < end; ++p) {
      int2 m0 = meta[p];
      float n0 = __int_as_float(m0.y);
      uint2 x0 = *(const uint2*)(hb + (size_t)m0.x * C + cb);
      acc.x += bfl(x0.x) * n0; acc.y += bfh(x0.x) * n0;
      acc.z += bfl(x0.y) * n0; acc.w += bfh(x0.y) * n0;
    }
  } else {
    for (; p + 4 <= end; p += 4) {
      int2 m0 = meta[p], m1 = meta[p + 1], m2 = meta[p + 2], m3 = meta[p + 3];
      float n0 = __int_as_float(m0.y), n1 = __int_as_float(m1.y);
      float n2 = __int_as_float(m2.y), n3 = __int_as_float(m3.y);
      float4 x0 = *(const float4*)(h + (size_t)m0.x * C + cb);
      float4 x1 = *(const float4*)(h + (size_t)m1.x * C + cb);
      float4 x2 = *(const float4*)(h + (size_t)m2.x * C + cb);
      float4 x3 = *(const float4*)(h + (size_t)m3.x * C + cb);
      acc.x += x0.x * n0 + x1.x * n1 + x2.x * n2 + x3.x * n3;
      acc.y += x0.y * n0 + x1.y * n1 + x2.y * n2 + x3.y * n3;
      acc.z += x0.z * n0 + x1.z * n1 + x2.z * n2 + x3.z * n3;
      acc.w += x0.w * n0 + x1.w * n1 + x2.w * n2 + x3.w * n3;
    }
    for (; p < end; ++p) {
      int2 m0 = meta[p];
      float n0 = __int_as_float(m0.y);
      float4 x0 = *(const float4*)(h + (size_t)m0.x * C + cb);
      acc.x += x0.x * n0; acc.y += x0.y * n0; acc.z += x0.z * n0; acc.w += x0.w * n0;
    }
  }
  if (OUT_BF) {
    uint2 pk;
    pk.x = f2bf(acc.x) | ((unsigned int)f2bf(acc.y) << 16);
    pk.y = f2bf(acc.z) | ((unsigned int)f2bf(acc.w) << 16);
    *(uint2*)(aggb + (size_t)v * C + cb) = pk;
  } else {
    *(float4*)(aggf + (size_t)v * C + cb) = acc;
  }
}

// ---- kH: x = agg @ W^T + b + h ; LN ; exact GELU  (bf16 MFMA) ----
#define TM 64

template <int IN_BF>
__launch_bounds__(256, 3)
__global__ void k_mfma_ln_gelu(const float* __restrict__ aggf,
                               const unsigned short* __restrict__ aggb,
                               const float* __restrict__ h,
                               const unsigned short* __restrict__ Wb,
                               const float* __restrict__ b,
                               const float* __restrict__ gamma, const float* __restrict__ beta,
                               float* __restrict__ out, int n) {
  __shared__ char lds[48 * 1024];
  char* Wl = lds;              // 32 KB bf16 [128][128], swizzled
  char* Al = lds + 32768;      // 16 KB bf16 [64][128],  swizzled
  const int tid = threadIdx.x;
  const int row0 = blockIdx.x * TM;

  // stage W (bf16, 2048 x 16B units), swizzle: byte ^= (row&7)<<4
  #pragma unroll
  for (int i = 0; i < 8; ++i) {
    int u = tid + i * 256;
    int j = u >> 4, un = u & 15;
    uint4 w = ((const uint4*)Wb)[u];
    *(uint4*)(Wl + j * 256 + ((un * 16) ^ ((j & 7) << 4))) = w;
  }
  // stage A tile (2048 8B units: row = u>>5, unit = u&31)
  #pragma unroll
  for (int i = 0; i < 8; ++i) {
    int u = tid + i * 256;
    int j = u >> 5;
    int rr = row0 + j; if (rr >= n) rr = n - 1;
    uint2 pk;
    if (IN_BF) {
      pk = ((const uint2*)(aggb + (size_t)rr * C))[u & 31];
    } else {
      float4 a = ((const float4*)(aggf + (size_t)rr * C))[u & 31];
      pk.x = f2bf(a.x) | ((unsigned int)f2bf(a.y) << 16);
      pk.y = f2bf(a.z) | ((unsigned int)f2bf(a.w) << 16);
    }
    *(uint2*)(Al + j * 256 + (((u & 31) * 8) ^ ((j & 7) << 4))) = pk;
  }
  __syncthreads();

  const int lane = tid & 63;
  const int wt   = tid >> 6;
  const int c16  = lane & 15;
  const int quad = lane >> 4;

  f32x4 acc[8];
  #pragma unroll
  for (int jt = 0; jt < 8; ++jt) acc[jt] = (f32x4){0.f, 0.f, 0.f, 0.f};

  const int abase = (wt * 16 + c16) * 256;
  const int swz   = (c16 & 7) << 4;
  #pragma unroll
  for (int ks = 0; ks < 4; ++ks) {
    const int koff = ks * 64 + quad * 16;
    short8 af = *(const short8*)(Al + abase + (koff ^ swz));
    #pragma unroll
    for (int jt = 0; jt < 8; ++jt) {
      short8 bf = *(const short8*)(Wl + (jt * 16 + c16) * 256 + (koff ^ swz));
      acc[jt] = __builtin_amdgcn_mfma_f32_16x16x32_bf16(af, bf, acc[jt], 0, 0, 0);
    }
  }

  float bj[8], gj[8], btj[8];
  #pragma unroll
  for (int jt = 0; jt < 8; ++jt) {
    int j = jt * 16 + c16;
    bj[jt] = b[j]; gj[jt] = gamma[j]; btj[jt] = beta[j];
  }

  #pragma unroll
  for (int i = 0; i < 4; ++i) {
    const int row = row0 + wt * 16 + quad * 4 + i;
    const bool ok = row < n;
    const float* hrow = h + (size_t)row * C;
    float x[8];
    float s = 0.f, t2 = 0.f;
    #pragma unroll
    for (int jt = 0; jt < 8; ++jt) {
      float v = acc[jt][i] + bj[jt] + (ok ? hrow[jt * 16 + c16] : 0.f);
      x[jt] = v; s += v; t2 += v * v;
    }
    #pragma unroll
    for (int m = 8; m >= 1; m >>= 1) {
      s += __shfl_xor(s, m, 16); t2 += __shfl_xor(t2, m, 16);
    }
    const float inv = 1.0f / C;
    float mean = s * inv;
    float var  = t2 * inv - mean * mean;
    float rstd = rsqrtf(var + 1e-5f);
    if (ok) {
      float* orow = out + (size_t)row * C;
      #pragma unroll
      for (int jt = 0; jt < 8; ++jt) {
        float y = gj[jt] * ((x[jt] - mean) * rstd) + btj[jt];
        orow[jt * 16 + c16] = 0.5f * y * (1.0f + erff(y * 0.70710678118f));
      }
    }
  }
}

extern "C" void kernel_launch(void* const* d_in, const int* in_sizes, int n_in,
                              void* d_out, int out_size, void* d_ws, size_t ws_size,
                              hipStream_t stream) {
  const float* h     = (const float*)d_in[0];
  const int*   ei    = (const int*)d_in[1];
  const float* ew    = (const float*)d_in[2];
  const float* W     = (const float*)d_in[3];
  const float* b     = (const float*)d_in[4];
  const float* gamma = (const float*)d_in[5];
  const float* beta  = (const float*)d_in[6];

  const int n = in_sizes[0] / C;
  const int e = in_sizes[2];
  const int* src = ei;
  const int* dst = ei + e;

  float* out = (float*)d_out;

  // workspace layout
  int2* meta    = (int2*)d_ws;                          // e
  unsigned long long* packed = (unsigned long long*)(meta + e);  // n (8B aligned)
  int* slot     = (int*)(packed + n);                   // e
  float* d      = (float*)(slot + e);                   // n
  int* rowptr   = (int*)(d + n);                        // n+1
  int* sums     = rowptr + (n + 1);                     // <=256
  unsigned short* Wb = (unsigned short*)(sums + 256);   // C*C
  unsigned short* hb = Wb + C * C;                      // n*C
  unsigned short* aggb = hb + (size_t)n * C;            // n*C

  const size_t need_mid  = (size_t)((char*)(hb + (size_t)n * C) - (char*)d_ws);
  const size_t need_full = (size_t)((char*)(aggb + (size_t)n * C) - (char*)d_ws);
  const int mode = (ws_size >= need_full) ? 2 : (ws_size >= need_mid) ? 1 : 0;

  const int nb = (n + SCAN_CHUNK - 1) / SCAN_CHUNK;
  const int total4 = n * C / 4;

  if (mode >= 1)
    k_prep_all<1><<<1024, 256, 0, stream>>>(W, Wb, h, hb, total4, packed, n);
  else
    k_prep_all<0><<<1024, 256, 0, stream>>>(W, Wb, h, hb, total4, packed, n);

  k_edge_deg<<<(e + 255) / 256, 256, 0, stream>>>(dst, ew, packed, slot, e);
  k_scan1   <<<nb, 256, 0, stream>>>(packed, d, rowptr, sums, n);
  k_scan2   <<<1, 256, 0, stream>>>(sums, nb);
  k_scan3   <<<(n + 255) / 256, 256, 0, stream>>>(rowptr, sums, n, e);
  k_scatter <<<(e + 255) / 256, 256, 0, stream>>>(src, dst, ew, d, rowptr, slot, meta, e);

  const long gthreads = (long)n * 32;
  const int ggrid = (int)((gthreads + 255) / 256);
  const int mgrid = (n + TM - 1) / TM;

  if (mode == 2) {
    k_gather<1, 1><<<ggrid, 256, 0, stream>>>(rowptr, meta, d, h, hb, out, aggb, n);
    k_mfma_ln_gelu<1><<<mgrid, 256, 0, stream>>>(out, aggb, h, Wb, b, gamma, beta, out, n);
  } else if (mode == 1) {
    k_gather<1, 0><<<ggrid, 256, 0, stream>>>(rowptr, meta, d, h, hb, out, aggb, n);
    k_mfma_ln_gelu<0><<<mgrid, 256, 0, stream>>>(out, aggb, h, Wb, b, gamma, beta, out, n);
  } else {
    k_gather<0, 0><<<ggrid, 256, 0, stream>>>(rowptr, meta, d, h, hb, out, aggb, n);
    k_mfma_ln_gelu<0><<<mgrid, 256, 0, stream>>>(out, aggb, h, Wb, b, gamma, beta, out, n);
  }
}